// Round 13
// baseline (184.589 us; speedup 1.0000x reference)
//
#include <hip/hip_runtime.h>
#include <math.h>

// FBPINN: out(x) = sum_k w_k(x)*subnet_k(x) / sum_k w_k(x), x scalar in [0,1].
// Two dispatches:
//  1) build_tables: numerator table at TBL points, interleaved by slot:
//     g[i*4+s] = w_{klo(i)+s}(x_i)*o_{klo(i)+s}(x_i). Grid = 512 single-wave
//     blocks: (128-pt stretch, slot); subnet k block-uniform. Weights staged
//     once to LDS (9 coalesced float4 loads), then read with batched
//     ping-pong row buffers. KEY CHANGE vs R8-R11: each lane evaluates TWO
//     points (p, p+64), so each ds_read_b128 feeds 8 FMAs instead of 4 --
//     FMA issue (2x4.3K cyc/wave) now covers the read stream's latency,
//     which R12 analysis showed was the invariant ~30K-cycle per-wave chain
//     across all previous delivery mechanisms. 4 slots still cover a 128-pt
//     stretch (3.72 + 0.124 < 4). No atomics, no zero-fill, no syncthreads.
//  2) eval_lerp: two float4 loads fetch the 8 interleaved entries; sum of 4
//     lerps = lerp of sum; denominator ANALYTIC (<=4 cosine windows).
// Lerp error ~2.5e-6 at TBL=16384 << 7.3e-3 threshold (bf16 floor 1.95e-3).

#define KSUB 16
#define NW 32
#define TBL 16384
#define PSTR 128              // points per stretch
#define NSTRETCH (TBL / PSTR) // 128
#define SLOTS 4
// LDS layout (floats): W1[1024] W2[1024] W0[32] B0[32] B1[32] B2[32] W3[32]
#define OW1 0
#define OW2 1024
#define OW0 2048
#define OB0 2080
#define OB1 2112
#define OB2 2144
#define OW3 2176
#define LDSF 2208

// tanh(x) = 1 - 2/(exp(2x)+1); v_exp_f32 is exp2 -> scale by 2*log2(e).
static __device__ __forceinline__ float fast_tanh(float v) {
    float e = __builtin_amdgcn_exp2f(v * 2.8853900817779268f);
    return 1.0f - 2.0f * __builtin_amdgcn_rcpf(e + 1.0f);
}

static __device__ __forceinline__ float cos_pi(float u) {
    return __builtin_amdgcn_cosf(0.5f * u);   // v_cos takes revolutions
}

static __device__ __forceinline__ float window_w(float x, int k) {
    const float invTW = 20.0f;  // 1/0.05
    float xmin = (float)k * 0.0625f - 0.06f;
    float xmax = (float)(k + 1) * 0.0625f + 0.06f;
    float up = (x - xmin + 0.025f) * invTW;
    float dn = (xmax + 0.025f - x) * invTW;
    up = fminf(fmaxf(up, 0.0f), 1.0f);
    dn = fminf(fmaxf(dn, 0.0f), 1.0f);
    return 0.25f * (1.0f - cos_pi(up)) * (1.0f - cos_pi(dn));
}

// Active subnets at x: k in (16x-2.36, 16x+1.36) => at most 4, klo..klo+3.
static __device__ __forceinline__ float den_analytic(float xv) {
    int klo = (int)ceilf(16.0f * xv - 2.36f);
    float den = 0.f;
#pragma unroll
    for (int j = 0; j < 4; ++j) {
        int k = klo + j;
        if (k >= 0 && k < KSUB) den += window_w(xv, k);
    }
    return den;
}

// Batched row load: 8 ds_read_b128 + 1 ds_read_b32.
#define LOADROW(buf, bvar, wofs, bofs, o)                                   \
    {                                                                       \
        _Pragma("unroll")                                                   \
        for (int q = 0; q < 8; ++q)                                         \
            buf[q] = *reinterpret_cast<const float4*>(&R[(wofs) + (o) * NW + 4 * q]); \
        bvar = R[(bofs) + (o)];                                             \
    }

// Dual-point row FMA: each weight element feeds both points.
#define FMAROW2(buf, bvar, hA, hB, dstA, dstB)                              \
    {                                                                       \
        float a0 = bvar, a1 = 0.f, a2 = 0.f, a3 = 0.f;                      \
        float c0 = bvar, c1 = 0.f, c2 = 0.f, c3 = 0.f;                      \
        _Pragma("unroll")                                                   \
        for (int q = 0; q < 8; ++q) {                                       \
            a0 = fmaf(buf[q].x, hA[4 * q + 0], a0);                         \
            c0 = fmaf(buf[q].x, hB[4 * q + 0], c0);                         \
            a1 = fmaf(buf[q].y, hA[4 * q + 1], a1);                         \
            c1 = fmaf(buf[q].y, hB[4 * q + 1], c1);                         \
            a2 = fmaf(buf[q].z, hA[4 * q + 2], a2);                         \
            c2 = fmaf(buf[q].z, hB[4 * q + 2], c2);                         \
            a3 = fmaf(buf[q].w, hA[4 * q + 3], a3);                         \
            c3 = fmaf(buf[q].w, hB[4 * q + 3], c3);                         \
        }                                                                   \
        dstA = fast_tanh((a0 + a1) + (a2 + a3));                            \
        dstB = fast_tanh((c0 + c1) + (c2 + c3));                            \
    }

// grid = NSTRETCH*SLOTS = 512 single-wave blocks.
__global__ __launch_bounds__(64, 2) void build_tables(
    const float* __restrict__ W0, const float* __restrict__ B0,
    const float* __restrict__ W1, const float* __restrict__ B1,
    const float* __restrict__ W2, const float* __restrict__ B2,
    const float* __restrict__ W3, const float* __restrict__ B3,
    float* __restrict__ g)
{
    __shared__ float R[LDSF];   // 8.6 KB weight region

    const int lane = threadIdx.x;         // 0..63
    const int str  = blockIdx.x >> 2;
    const int slot = blockIdx.x & 3;
    const int p0   = str * PSTR + lane;
    const int p1   = p0 + 64;
    const float inv = 1.0f / (float)(TBL - 1);
    const float x0  = (float)p0 * inv;
    const float x1  = (float)p1 * inv;

    float x_lo = (float)(str * PSTR) * inv;
    int klo_b = (int)ceilf(16.0f * x_lo - 2.36f);
    const int k  = klo_b + slot;          // block-uniform
    const int kc = min(max(k, 0), KSUB - 1);

    // ---- stage this subnet's weights into LDS (one memory round-trip) ----
    {
        const float4* gW1 = reinterpret_cast<const float4*>(&W1[kc * NW * NW]);
        const float4* gW2 = reinterpret_cast<const float4*>(&W2[kc * NW * NW]);
        float4 t0 = gW1[0 * 64 + lane];
        float4 t1 = gW1[1 * 64 + lane];
        float4 t2 = gW1[2 * 64 + lane];
        float4 t3 = gW1[3 * 64 + lane];
        float4 t4 = gW2[0 * 64 + lane];
        float4 t5 = gW2[1 * 64 + lane];
        float4 t6 = gW2[2 * 64 + lane];
        float4 t7 = gW2[3 * 64 + lane];
        float4 t8;
        const int a = lane >> 3;          // 0..7 (0..4 carry data)
        const int e = (lane & 7) * 4;
        const float* sp = (a == 0) ? &W0[kc * NW] :
                          (a == 1) ? &B0[kc * NW] :
                          (a == 2) ? &B1[kc * NW] :
                          (a == 3) ? &B2[kc * NW] : &W3[kc * NW];
        if (a < 5) t8 = *reinterpret_cast<const float4*>(&sp[e]);
        *reinterpret_cast<float4*>(&R[OW1 + 0 * 256 + lane * 4]) = t0;
        *reinterpret_cast<float4*>(&R[OW1 + 1 * 256 + lane * 4]) = t1;
        *reinterpret_cast<float4*>(&R[OW1 + 2 * 256 + lane * 4]) = t2;
        *reinterpret_cast<float4*>(&R[OW1 + 3 * 256 + lane * 4]) = t3;
        *reinterpret_cast<float4*>(&R[OW2 + 0 * 256 + lane * 4]) = t4;
        *reinterpret_cast<float4*>(&R[OW2 + 1 * 256 + lane * 4]) = t5;
        *reinterpret_cast<float4*>(&R[OW2 + 2 * 256 + lane * 4]) = t6;
        *reinterpret_cast<float4*>(&R[OW2 + 3 * 256 + lane * 4]) = t7;
        if (a < 5)
            *reinterpret_cast<float4*>(&R[OW0 + a * 32 + e]) = t8;
    }
    // same-wave ds_write -> ds_read ordering handled by lgkmcnt (R8-proven).

    // ---- evaluate subnet kc at BOTH of this lane's points ----
    const float INVS = 10.958904109589041f;  // 1/0.09125 (uniform scale)
    const float ctr  = ((float)kc + 0.5f) * 0.0625f;
    float xnA = (x0 - ctr) * INVS;
    float xnB = (x1 - ctr) * INVS;

    float h0a[NW], h0b[NW], h1a[NW], h1b[NW];
    // layer 0: batched (16 reads), each weight feeds both points
    {
        float4 wv[8], bv[8];
#pragma unroll
        for (int q = 0; q < 8; ++q)
            wv[q] = *reinterpret_cast<const float4*>(&R[OW0 + 4 * q]);
#pragma unroll
        for (int q = 0; q < 8; ++q)
            bv[q] = *reinterpret_cast<const float4*>(&R[OB0 + 4 * q]);
#pragma unroll
        for (int q = 0; q < 8; ++q) {
            h0a[4 * q + 0] = fast_tanh(fmaf(wv[q].x, xnA, bv[q].x));
            h0b[4 * q + 0] = fast_tanh(fmaf(wv[q].x, xnB, bv[q].x));
            h0a[4 * q + 1] = fast_tanh(fmaf(wv[q].y, xnA, bv[q].y));
            h0b[4 * q + 1] = fast_tanh(fmaf(wv[q].y, xnB, bv[q].y));
            h0a[4 * q + 2] = fast_tanh(fmaf(wv[q].z, xnA, bv[q].z));
            h0b[4 * q + 2] = fast_tanh(fmaf(wv[q].z, xnB, bv[q].z));
            h0a[4 * q + 3] = fast_tanh(fmaf(wv[q].w, xnA, bv[q].w));
            h0b[4 * q + 3] = fast_tanh(fmaf(wv[q].w, xnB, bv[q].w));
        }
    }
    // layers 1 & 2: ping-pong row buffers, dual-point FMAs
    {
        float4 bufA[8], bufB[8];
        float bA, bB;
        LOADROW(bufA, bA, OW1, OB1, 0);
#pragma unroll
        for (int o = 0; o < NW; o += 2) {
            LOADROW(bufB, bB, OW1, OB1, o + 1);
            FMAROW2(bufA, bA, h0a, h0b, h1a[o], h1b[o]);
            if (o + 2 < NW) LOADROW(bufA, bA, OW1, OB1, o + 2);
            FMAROW2(bufB, bB, h0a, h0b, h1a[o + 1], h1b[o + 1]);
        }
        LOADROW(bufA, bA, OW2, OB2, 0);
#pragma unroll
        for (int o = 0; o < NW; o += 2) {
            LOADROW(bufB, bB, OW2, OB2, o + 1);
            FMAROW2(bufA, bA, h1a, h1b, h0a[o], h0b[o]);   // h0 reused as h2
            if (o + 2 < NW) LOADROW(bufA, bA, OW2, OB2, o + 2);
            FMAROW2(bufB, bB, h1a, h1b, h0a[o + 1], h0b[o + 1]);
        }
    }
    // layer 3: batched, dual
    float outA, outB;
    {
        float4 wv[8];
#pragma unroll
        for (int q = 0; q < 8; ++q)
            wv[q] = *reinterpret_cast<const float4*>(&R[OW3 + 4 * q]);
        float a0 = B3[kc], a1 = 0.f, a2 = 0.f, a3 = 0.f;
        float c0 = B3[kc], c1 = 0.f, c2 = 0.f, c3 = 0.f;
#pragma unroll
        for (int q = 0; q < 8; ++q) {
            a0 = fmaf(wv[q].x, h0a[4 * q + 0], a0);
            c0 = fmaf(wv[q].x, h0b[4 * q + 0], c0);
            a1 = fmaf(wv[q].y, h0a[4 * q + 1], a1);
            c1 = fmaf(wv[q].y, h0b[4 * q + 1], c1);
            a2 = fmaf(wv[q].z, h0a[4 * q + 2], a2);
            c2 = fmaf(wv[q].z, h0b[4 * q + 2], c2);
            a3 = fmaf(wv[q].w, h0a[4 * q + 3], a3);
            c3 = fmaf(wv[q].w, h0b[4 * q + 3], c3);
        }
        outA = (a0 + a1) + (a2 + a3);
        outB = (c0 + c1) + (c2 + c3);
    }

    const bool act = (k >= 0) && (k < KSUB);
    float wA = window_w(x0, kc);
    float wB = window_w(x1, kc);
    g[p0 * 4 + slot] = act ? wA * outA : 0.0f;
    g[p1 * 4 + slot] = act ? wB * outB : 0.0f;
}

static __device__ __forceinline__ float eval_point(
    float xj, const float* __restrict__ g)
{
    const float scaleT = (float)(TBL - 1);
    float t = fminf(fmaxf(xj * scaleT, 0.0f), scaleT);
    int i0 = (int)t;
    if (i0 > TBL - 2) i0 = TBL - 2;
    float f = t - (float)i0;
    float4 a = *reinterpret_cast<const float4*>(&g[i0 * 4]);
    float4 b = *reinterpret_cast<const float4*>(&g[i0 * 4 + 4]);
    float n0 = (a.x + a.y) + (a.z + a.w);
    float n1 = (b.x + b.y) + (b.z + b.w);
    float num = fmaf(f, n1 - n0, n0);
    float den = den_analytic(xj);
    return num * __builtin_amdgcn_rcpf(den + 1e-12f);
}

__global__ void eval_lerp(const float* __restrict__ x,
                          const float* __restrict__ g,
                          float* __restrict__ out, int N)
{
    int idx = blockIdx.x * blockDim.x + threadIdx.x;
    int base = idx * 4;
    if (base + 3 < N) {
        float4 xv = *reinterpret_cast<const float4*>(&x[base]);
        float4 r;
        r.x = eval_point(xv.x, g);
        r.y = eval_point(xv.y, g);
        r.z = eval_point(xv.z, g);
        r.w = eval_point(xv.w, g);
        *reinterpret_cast<float4*>(&out[base]) = r;
    } else {
        for (int j = base; j < N; ++j) out[j] = eval_point(x[j], g);
    }
}

// ---- fallback path (tiny ws only): direct evaluation via global loads ----
static __device__ __forceinline__ float subnet_eval_g(
    float xn, int kc,
    const float* __restrict__ W0, const float* __restrict__ B0,
    const float* __restrict__ W1, const float* __restrict__ B1,
    const float* __restrict__ W2, const float* __restrict__ B2,
    const float* __restrict__ W3, const float* __restrict__ B3)
{
    float h0[NW], h1[NW];
#pragma unroll
    for (int o = 0; o < NW; ++o)
        h0[o] = fast_tanh(fmaf(W0[kc * NW + o], xn, B0[kc * NW + o]));
#pragma unroll
    for (int o = 0; o < NW; ++o) {
        float a = B1[kc * NW + o];
        const float* row = &W1[kc * NW * NW + o * NW];
#pragma unroll
        for (int j = 0; j < NW; ++j) a = fmaf(row[j], h0[j], a);
        h1[o] = fast_tanh(a);
    }
#pragma unroll
    for (int o = 0; o < NW; ++o) {
        float a = B2[kc * NW + o];
        const float* row = &W2[kc * NW * NW + o * NW];
#pragma unroll
        for (int j = 0; j < NW; ++j) a = fmaf(row[j], h1[j], a);
        h0[o] = fast_tanh(a);
    }
    float a = B3[kc];
#pragma unroll
    for (int j = 0; j < NW; ++j) a = fmaf(W3[kc * NW + j], h0[j], a);
    return a;
}

__global__ void direct_eval(
    const float* __restrict__ x,
    const float* __restrict__ W0, const float* __restrict__ B0,
    const float* __restrict__ W1, const float* __restrict__ B1,
    const float* __restrict__ W2, const float* __restrict__ B2,
    const float* __restrict__ W3, const float* __restrict__ B3,
    float* __restrict__ out, int N)
{
    int n = blockIdx.x * blockDim.x + threadIdx.x;
    if (n >= N) return;
    float xv = x[n];
    float num = 0.f, den = 0.f;
    for (int k = 0; k < KSUB; ++k) {
        float w = window_w(xv, k);
        if (w <= 0.0f) continue;
        float xn = (xv - ((float)k + 0.5f) * 0.0625f) * 10.958904109589041f;
        float o = subnet_eval_g(xn, k, W0, B0, W1, B1, W2, B2, W3, B3);
        num += w * o;
        den += w;
    }
    out[n] = num * __builtin_amdgcn_rcpf(den + 1e-12f);
}

extern "C" void kernel_launch(void* const* d_in, const int* in_sizes, int n_in,
                              void* d_out, int out_size, void* d_ws, size_t ws_size,
                              hipStream_t stream) {
    const float* x  = (const float*)d_in[0];
    const float* W0 = (const float*)d_in[1];
    const float* B0 = (const float*)d_in[2];
    const float* W1 = (const float*)d_in[3];
    const float* B1 = (const float*)d_in[4];
    const float* W2 = (const float*)d_in[5];
    const float* B2 = (const float*)d_in[6];
    const float* W3 = (const float*)d_in[7];
    const float* B3 = (const float*)d_in[8];
    float* out = (float*)d_out;
    const int N = in_sizes[0];

    if ((size_t)TBL * 4 * sizeof(float) <= ws_size) {
        float* g = (float*)d_ws;
        build_tables<<<NSTRETCH * SLOTS, 64, 0, stream>>>(
            W0, B0, W1, B1, W2, B2, W3, B3, g);
        int nv = (N + 3) / 4;
        eval_lerp<<<(nv + 255) / 256, 256, 0, stream>>>(x, g, out, N);
    } else {
        direct_eval<<<(N + 255) / 256, 256, 0, stream>>>(
            x, W0, B0, W1, B1, W2, B2, W3, B3, out, N);
    }
}

// Round 14
// 27.515 us; speedup vs baseline: 6.7086x; 6.7086x over previous
//
#include <hip/hip_runtime.h>
#include <math.h>

// FBPINN: out(x) = sum_k w_k(x)*subnet_k(x) / sum_k w_k(x), x scalar in [0,1].
// Two dispatches:
//  1) build_tables: numerator table at TBL points, interleaved by slot:
//     g[i*4+s] = w_{klo(i)+s}(x_i)*o_{klo(i)+s}(x_i). Grid = 512 single-wave
//     blocks: (128-pt stretch, slot); subnet k block-uniform. Weights staged
//     once to LDS (9 coalesced float4 loads). EACH LANE EVALUATES TWO POINTS
//     (p, p+64): each ds_read_b128 quad feeds 8 FMAs (4 per point), halving
//     chip-wide LDS-read issue at fixed T. R13 tried this with ping-pong
//     buffers + launch_bounds(64,2) and SPILLED (VGPR capped 128, 299MB
//     scratch writes, 184us). This version reads quads directly (peak live
//     ~170 VGPR, no cap) -> no spill. No atomics, no zero-fill, no syncs.
//  2) eval_lerp: two float4 loads fetch the 8 interleaved entries; sum of 4
//     lerps = lerp of sum; denominator ANALYTIC (<=4 cosine windows).
// Lerp error ~2.5e-6 at TBL=16384 << 7.3e-3 threshold (bf16 floor 1.95e-3).

#define KSUB 16
#define NW 32
#define TBL 16384
#define PSTR 128              // points per stretch (2 per lane)
#define NSTRETCH (TBL / PSTR) // 128
#define SLOTS 4               // active-k union over 128-pt stretch: 3.84 < 4
// LDS layout (floats): W1[1024] W2[1024] W0[32] B0[32] B1[32] B2[32] W3[32]
#define OW1 0
#define OW2 1024
#define OW0 2048
#define OB0 2080
#define OB1 2112
#define OB2 2144
#define OW3 2176
#define LDSF 2208

// tanh(x) = 1 - 2/(exp(2x)+1); v_exp_f32 is exp2 -> scale by 2*log2(e).
static __device__ __forceinline__ float fast_tanh(float v) {
    float e = __builtin_amdgcn_exp2f(v * 2.8853900817779268f);
    return 1.0f - 2.0f * __builtin_amdgcn_rcpf(e + 1.0f);
}

static __device__ __forceinline__ float cos_pi(float u) {
    return __builtin_amdgcn_cosf(0.5f * u);   // v_cos takes revolutions
}

static __device__ __forceinline__ float window_w(float x, int k) {
    const float invTW = 20.0f;  // 1/0.05
    float xmin = (float)k * 0.0625f - 0.06f;
    float xmax = (float)(k + 1) * 0.0625f + 0.06f;
    float up = (x - xmin + 0.025f) * invTW;
    float dn = (xmax + 0.025f - x) * invTW;
    up = fminf(fmaxf(up, 0.0f), 1.0f);
    dn = fminf(fmaxf(dn, 0.0f), 1.0f);
    return 0.25f * (1.0f - cos_pi(up)) * (1.0f - cos_pi(dn));
}

// Active subnets at x: k in (16x-2.36, 16x+1.36) => at most 4, klo..klo+3.
static __device__ __forceinline__ float den_analytic(float xv) {
    int klo = (int)ceilf(16.0f * xv - 2.36f);
    float den = 0.f;
#pragma unroll
    for (int j = 0; j < 4; ++j) {
        int k = klo + j;
        if (k >= 0 && k < KSUB) den += window_w(xv, k);
    }
    return den;
}

// grid = NSTRETCH*SLOTS = 512 single-wave blocks.
__global__ __launch_bounds__(64) void build_tables(
    const float* __restrict__ W0, const float* __restrict__ B0,
    const float* __restrict__ W1, const float* __restrict__ B1,
    const float* __restrict__ W2, const float* __restrict__ B2,
    const float* __restrict__ W3, const float* __restrict__ B3,
    float* __restrict__ g)
{
    __shared__ float R[LDSF];   // 8.6 KB weight region

    const int lane = threadIdx.x;         // 0..63
    const int str  = blockIdx.x >> 2;
    const int slot = blockIdx.x & 3;
    const int p0   = str * PSTR + lane;
    const int p1   = p0 + 64;
    const float inv = 1.0f / (float)(TBL - 1);
    const float x0  = (float)p0 * inv;
    const float x1  = (float)p1 * inv;

    float x_lo = (float)(str * PSTR) * inv;
    int klo_b = (int)ceilf(16.0f * x_lo - 2.36f);
    const int k  = klo_b + slot;          // block-uniform
    const int kc = min(max(k, 0), KSUB - 1);

    // ---- stage this subnet's weights into LDS (one memory round-trip) ----
    {
        const float4* gW1 = reinterpret_cast<const float4*>(&W1[kc * NW * NW]);
        const float4* gW2 = reinterpret_cast<const float4*>(&W2[kc * NW * NW]);
        float4 t0 = gW1[0 * 64 + lane];
        float4 t1 = gW1[1 * 64 + lane];
        float4 t2 = gW1[2 * 64 + lane];
        float4 t3 = gW1[3 * 64 + lane];
        float4 t4 = gW2[0 * 64 + lane];
        float4 t5 = gW2[1 * 64 + lane];
        float4 t6 = gW2[2 * 64 + lane];
        float4 t7 = gW2[3 * 64 + lane];
        float4 t8;
        const int a = lane >> 3;          // 0..7 (0..4 carry data)
        const int e = (lane & 7) * 4;
        const float* sp = (a == 0) ? &W0[kc * NW] :
                          (a == 1) ? &B0[kc * NW] :
                          (a == 2) ? &B1[kc * NW] :
                          (a == 3) ? &B2[kc * NW] : &W3[kc * NW];
        if (a < 5) t8 = *reinterpret_cast<const float4*>(&sp[e]);
        *reinterpret_cast<float4*>(&R[OW1 + 0 * 256 + lane * 4]) = t0;
        *reinterpret_cast<float4*>(&R[OW1 + 1 * 256 + lane * 4]) = t1;
        *reinterpret_cast<float4*>(&R[OW1 + 2 * 256 + lane * 4]) = t2;
        *reinterpret_cast<float4*>(&R[OW1 + 3 * 256 + lane * 4]) = t3;
        *reinterpret_cast<float4*>(&R[OW2 + 0 * 256 + lane * 4]) = t4;
        *reinterpret_cast<float4*>(&R[OW2 + 1 * 256 + lane * 4]) = t5;
        *reinterpret_cast<float4*>(&R[OW2 + 2 * 256 + lane * 4]) = t6;
        *reinterpret_cast<float4*>(&R[OW2 + 3 * 256 + lane * 4]) = t7;
        if (a < 5)
            *reinterpret_cast<float4*>(&R[OW0 + a * 32 + e]) = t8;
    }
    // same-wave ds_write -> ds_read ordering handled by lgkmcnt (R8-proven).

    // ---- evaluate subnet kc at BOTH of this lane's points ----
    const float INVS = 10.958904109589041f;  // 1/0.09125 (uniform scale)
    const float ctr  = ((float)kc + 0.5f) * 0.0625f;
    float xnA = (x0 - ctr) * INVS;
    float xnB = (x1 - ctr) * INVS;

    float h0a[NW], h0b[NW], h1a[NW], h1b[NW];
    // layer 0: read quads directly, each feeds both points
#pragma unroll
    for (int q = 0; q < 8; ++q) {
        float4 wv = *reinterpret_cast<const float4*>(&R[OW0 + 4 * q]);
        float4 bv = *reinterpret_cast<const float4*>(&R[OB0 + 4 * q]);
        h0a[4 * q + 0] = fast_tanh(fmaf(wv.x, xnA, bv.x));
        h0b[4 * q + 0] = fast_tanh(fmaf(wv.x, xnB, bv.x));
        h0a[4 * q + 1] = fast_tanh(fmaf(wv.y, xnA, bv.y));
        h0b[4 * q + 1] = fast_tanh(fmaf(wv.y, xnB, bv.y));
        h0a[4 * q + 2] = fast_tanh(fmaf(wv.z, xnA, bv.z));
        h0b[4 * q + 2] = fast_tanh(fmaf(wv.z, xnB, bv.z));
        h0a[4 * q + 3] = fast_tanh(fmaf(wv.w, xnA, bv.w));
        h0b[4 * q + 3] = fast_tanh(fmaf(wv.w, xnB, bv.w));
    }
    // layer 1: per row, read quad -> 8 FMAs (dual point)
#pragma unroll
    for (int o = 0; o < NW; ++o) {
        float bb = R[OB1 + o];
        float a0 = bb, a1 = 0.f, a2 = 0.f, a3 = 0.f;
        float c0 = bb, c1 = 0.f, c2 = 0.f, c3 = 0.f;
#pragma unroll
        for (int q = 0; q < 8; ++q) {
            float4 wv = *reinterpret_cast<const float4*>(&R[OW1 + o * NW + 4 * q]);
            a0 = fmaf(wv.x, h0a[4 * q + 0], a0);
            c0 = fmaf(wv.x, h0b[4 * q + 0], c0);
            a1 = fmaf(wv.y, h0a[4 * q + 1], a1);
            c1 = fmaf(wv.y, h0b[4 * q + 1], c1);
            a2 = fmaf(wv.z, h0a[4 * q + 2], a2);
            c2 = fmaf(wv.z, h0b[4 * q + 2], c2);
            a3 = fmaf(wv.w, h0a[4 * q + 3], a3);
            c3 = fmaf(wv.w, h0b[4 * q + 3], c3);
        }
        h1a[o] = fast_tanh((a0 + a1) + (a2 + a3));
        h1b[o] = fast_tanh((c0 + c1) + (c2 + c3));
    }
    // layer 2: same, h0 arrays reused as h2
#pragma unroll
    for (int o = 0; o < NW; ++o) {
        float bb = R[OB2 + o];
        float a0 = bb, a1 = 0.f, a2 = 0.f, a3 = 0.f;
        float c0 = bb, c1 = 0.f, c2 = 0.f, c3 = 0.f;
#pragma unroll
        for (int q = 0; q < 8; ++q) {
            float4 wv = *reinterpret_cast<const float4*>(&R[OW2 + o * NW + 4 * q]);
            a0 = fmaf(wv.x, h1a[4 * q + 0], a0);
            c0 = fmaf(wv.x, h1b[4 * q + 0], c0);
            a1 = fmaf(wv.y, h1a[4 * q + 1], a1);
            c1 = fmaf(wv.y, h1b[4 * q + 1], c1);
            a2 = fmaf(wv.z, h1a[4 * q + 2], a2);
            c2 = fmaf(wv.z, h1b[4 * q + 2], c2);
            a3 = fmaf(wv.w, h1a[4 * q + 3], a3);
            c3 = fmaf(wv.w, h1b[4 * q + 3], c3);
        }
        h0a[o] = fast_tanh((a0 + a1) + (a2 + a3));
        h0b[o] = fast_tanh((c0 + c1) + (c2 + c3));
    }
    // layer 3: dual
    float outA, outB;
    {
        float bb = B3[kc];
        float a0 = bb, a1 = 0.f, a2 = 0.f, a3 = 0.f;
        float c0 = bb, c1 = 0.f, c2 = 0.f, c3 = 0.f;
#pragma unroll
        for (int q = 0; q < 8; ++q) {
            float4 wv = *reinterpret_cast<const float4*>(&R[OW3 + 4 * q]);
            a0 = fmaf(wv.x, h0a[4 * q + 0], a0);
            c0 = fmaf(wv.x, h0b[4 * q + 0], c0);
            a1 = fmaf(wv.y, h0a[4 * q + 1], a1);
            c1 = fmaf(wv.y, h0b[4 * q + 1], c1);
            a2 = fmaf(wv.z, h0a[4 * q + 2], a2);
            c2 = fmaf(wv.z, h0b[4 * q + 2], c2);
            a3 = fmaf(wv.w, h0a[4 * q + 3], a3);
            c3 = fmaf(wv.w, h0b[4 * q + 3], c3);
        }
        outA = (a0 + a1) + (a2 + a3);
        outB = (c0 + c1) + (c2 + c3);
    }

    const bool act = (k >= 0) && (k < KSUB);
    float wA = window_w(x0, kc);
    float wB = window_w(x1, kc);
    g[p0 * 4 + slot] = act ? wA * outA : 0.0f;
    g[p1 * 4 + slot] = act ? wB * outB : 0.0f;
}

static __device__ __forceinline__ float eval_point(
    float xj, const float* __restrict__ g)
{
    const float scaleT = (float)(TBL - 1);
    float t = fminf(fmaxf(xj * scaleT, 0.0f), scaleT);
    int i0 = (int)t;
    if (i0 > TBL - 2) i0 = TBL - 2;
    float f = t - (float)i0;
    float4 a = *reinterpret_cast<const float4*>(&g[i0 * 4]);
    float4 b = *reinterpret_cast<const float4*>(&g[i0 * 4 + 4]);
    float n0 = (a.x + a.y) + (a.z + a.w);
    float n1 = (b.x + b.y) + (b.z + b.w);
    float num = fmaf(f, n1 - n0, n0);
    float den = den_analytic(xj);
    return num * __builtin_amdgcn_rcpf(den + 1e-12f);
}

__global__ void eval_lerp(const float* __restrict__ x,
                          const float* __restrict__ g,
                          float* __restrict__ out, int N)
{
    int idx = blockIdx.x * blockDim.x + threadIdx.x;
    int base = idx * 4;
    if (base + 3 < N) {
        float4 xv = *reinterpret_cast<const float4*>(&x[base]);
        float4 r;
        r.x = eval_point(xv.x, g);
        r.y = eval_point(xv.y, g);
        r.z = eval_point(xv.z, g);
        r.w = eval_point(xv.w, g);
        *reinterpret_cast<float4*>(&out[base]) = r;
    } else {
        for (int j = base; j < N; ++j) out[j] = eval_point(x[j], g);
    }
}

// ---- fallback path (tiny ws only): direct evaluation via global loads ----
static __device__ __forceinline__ float subnet_eval_g(
    float xn, int kc,
    const float* __restrict__ W0, const float* __restrict__ B0,
    const float* __restrict__ W1, const float* __restrict__ B1,
    const float* __restrict__ W2, const float* __restrict__ B2,
    const float* __restrict__ W3, const float* __restrict__ B3)
{
    float h0[NW], h1[NW];
#pragma unroll
    for (int o = 0; o < NW; ++o)
        h0[o] = fast_tanh(fmaf(W0[kc * NW + o], xn, B0[kc * NW + o]));
#pragma unroll
    for (int o = 0; o < NW; ++o) {
        float a = B1[kc * NW + o];
        const float* row = &W1[kc * NW * NW + o * NW];
#pragma unroll
        for (int j = 0; j < NW; ++j) a = fmaf(row[j], h0[j], a);
        h1[o] = fast_tanh(a);
    }
#pragma unroll
    for (int o = 0; o < NW; ++o) {
        float a = B2[kc * NW + o];
        const float* row = &W2[kc * NW * NW + o * NW];
#pragma unroll
        for (int j = 0; j < NW; ++j) a = fmaf(row[j], h1[j], a);
        h0[o] = fast_tanh(a);
    }
    float a = B3[kc];
#pragma unroll
    for (int j = 0; j < NW; ++j) a = fmaf(W3[kc * NW + j], h0[j], a);
    return a;
}

__global__ void direct_eval(
    const float* __restrict__ x,
    const float* __restrict__ W0, const float* __restrict__ B0,
    const float* __restrict__ W1, const float* __restrict__ B1,
    const float* __restrict__ W2, const float* __restrict__ B2,
    const float* __restrict__ W3, const float* __restrict__ B3,
    float* __restrict__ out, int N)
{
    int n = blockIdx.x * blockDim.x + threadIdx.x;
    if (n >= N) return;
    float xv = x[n];
    float num = 0.f, den = 0.f;
    for (int k = 0; k < KSUB; ++k) {
        float w = window_w(xv, k);
        if (w <= 0.0f) continue;
        float xn = (xv - ((float)k + 0.5f) * 0.0625f) * 10.958904109589041f;
        float o = subnet_eval_g(xn, k, W0, B0, W1, B1, W2, B2, W3, B3);
        num += w * o;
        den += w;
    }
    out[n] = num * __builtin_amdgcn_rcpf(den + 1e-12f);
}

extern "C" void kernel_launch(void* const* d_in, const int* in_sizes, int n_in,
                              void* d_out, int out_size, void* d_ws, size_t ws_size,
                              hipStream_t stream) {
    const float* x  = (const float*)d_in[0];
    const float* W0 = (const float*)d_in[1];
    const float* B0 = (const float*)d_in[2];
    const float* W1 = (const float*)d_in[3];
    const float* B1 = (const float*)d_in[4];
    const float* W2 = (const float*)d_in[5];
    const float* B2 = (const float*)d_in[6];
    const float* W3 = (const float*)d_in[7];
    const float* B3 = (const float*)d_in[8];
    float* out = (float*)d_out;
    const int N = in_sizes[0];

    if ((size_t)TBL * 4 * sizeof(float) <= ws_size) {
        float* g = (float*)d_ws;
        build_tables<<<NSTRETCH * SLOTS, 64, 0, stream>>>(
            W0, B0, W1, B1, W2, B2, W3, B3, g);
        int nv = (N + 3) / 4;
        eval_lerp<<<(nv + 255) / 256, 256, 0, stream>>>(x, g, out, N);
    } else {
        direct_eval<<<(N + 255) / 256, 256, 0, stream>>>(
            x, W0, B0, W1, B1, W2, B2, W3, B3, out, N);
    }
}

// Round 15
// 18.484 us; speedup vs baseline: 9.9867x; 1.4886x over previous
//
#include <hip/hip_runtime.h>
#include <math.h>

// FBPINN: out(x) = sum_k w_k(x)*subnet_k(x) / sum_k w_k(x), x scalar in [0,1].
// Two dispatches:
//  1) build_tables, POINT-PER-QUAD: block = (64-pt stretch, slot); 256 thr.
//     Lane = (point p, row-group m): lane computes 8 of 32 rows per layer;
//     activations exchanged intra-quad via __shfl_xor(1/2/3). Cuts per-wave
//     chain ~30K->~2K cycles (R9/R11/R13 pinned build to the per-wave serial
//     chain) AND raises occupancy to 4 waves/SIMD (4096 waves). Weights in
//     LDS TRANSPOSED, stride 36: b128-aligned, m-groups hit banks
//     {0,8,16,24} -> conflict-free broadcast reads.
//  2) eval_lerp: two float4 loads fetch 8 interleaved table entries; sum of
//     4 lerps = lerp of sum; denominator ANALYTIC. (R9/R11/R13-validated.)
// Lerp error ~2.5e-6 at TBL=16384 << 7.3e-3 threshold (bf16 floor 1.95e-3).

#define KSUB 16
#define NW 32
#define TBL 16384
#define NSTR (TBL / 64)       // 256 stretches
#define SLOTS 4               // active-k union over 64-pt stretch <= 4 ints
#define STR36 36              // padded transposed row stride (floats)
// LDS offsets (floats)
#define OW1T 0                // [32][36] transposed W1
#define OW2T 1152             // [32][36] transposed W2
#define OT0  2304             // W0[32] B0[32] B1[32] B2[32] W3[32]
#define LDSF 2464

// tanh(x) = 1 - 2/(exp(2x)+1); v_exp_f32 is exp2 -> scale by 2*log2(e).
static __device__ __forceinline__ float fast_tanh(float v) {
    float e = __builtin_amdgcn_exp2f(v * 2.8853900817779268f);
    return 1.0f - 2.0f * __builtin_amdgcn_rcpf(e + 1.0f);
}

static __device__ __forceinline__ float cos_pi(float u) {
    return __builtin_amdgcn_cosf(0.5f * u);   // v_cos takes revolutions
}

static __device__ __forceinline__ float window_w(float x, int k) {
    const float invTW = 20.0f;  // 1/0.05
    float xmin = (float)k * 0.0625f - 0.06f;
    float xmax = (float)(k + 1) * 0.0625f + 0.06f;
    float up = (x - xmin + 0.025f) * invTW;
    float dn = (xmax + 0.025f - x) * invTW;
    up = fminf(fmaxf(up, 0.0f), 1.0f);
    dn = fminf(fmaxf(dn, 0.0f), 1.0f);
    return 0.25f * (1.0f - cos_pi(up)) * (1.0f - cos_pi(dn));
}

// Active subnets at x: k in (16x-2.36, 16x+1.36) => at most 4, klo..klo+3.
static __device__ __forceinline__ float den_analytic(float xv) {
    int klo = (int)ceilf(16.0f * xv - 2.36f);
    float den = 0.f;
#pragma unroll
    for (int j = 0; j < 4; ++j) {
        int k = klo + j;
        if (k >= 0 && k < KSUB) den += window_w(xv, k);
    }
    return den;
}

// One hidden layer, quad-split: lane owns rows [m*8, m*8+8).
// hin[8] = lane's 8 activations; out 8 new activations. WT = transposed
// weight base (LDS), bias at R[bofs + m*8 + j].
#define QLAYER(WTOFS, BOFS, hin, hout)                                      \
    {                                                                       \
        float acc[8];                                                       \
        _Pragma("unroll")                                                   \
        for (int j = 0; j < 8; ++j) acc[j] = R[(BOFS) + m8 + j];            \
        _Pragma("unroll")                                                   \
        for (int e = 0; e < 4; ++e) {                                       \
            float v[8];                                                     \
            _Pragma("unroll")                                               \
            for (int j2 = 0; j2 < 8; ++j2)                                  \
                v[j2] = e ? __shfl_xor(hin[j2], e) : hin[j2];               \
            const int src8 = ((m ^ e) << 3);                                \
            _Pragma("unroll")                                               \
            for (int j2 = 0; j2 < 8; ++j2) {                                \
                float4 wA = *reinterpret_cast<const float4*>(               \
                    &R[(WTOFS) + (src8 + j2) * STR36 + m8]);                \
                float4 wB = *reinterpret_cast<const float4*>(               \
                    &R[(WTOFS) + (src8 + j2) * STR36 + m8 + 4]);            \
                acc[0] = fmaf(wA.x, v[j2], acc[0]);                         \
                acc[1] = fmaf(wA.y, v[j2], acc[1]);                         \
                acc[2] = fmaf(wA.z, v[j2], acc[2]);                         \
                acc[3] = fmaf(wA.w, v[j2], acc[3]);                         \
                acc[4] = fmaf(wB.x, v[j2], acc[4]);                         \
                acc[5] = fmaf(wB.y, v[j2], acc[5]);                         \
                acc[6] = fmaf(wB.z, v[j2], acc[6]);                         \
                acc[7] = fmaf(wB.w, v[j2], acc[7]);                         \
            }                                                               \
        }                                                                   \
        _Pragma("unroll")                                                   \
        for (int j = 0; j < 8; ++j) hout[j] = fast_tanh(acc[j]);            \
    }

// grid = NSTR*SLOTS = 1024 blocks x 256 threads (4 waves, 16 pts/wave).
__global__ __launch_bounds__(256) void build_tables(
    const float* __restrict__ W0, const float* __restrict__ B0,
    const float* __restrict__ W1, const float* __restrict__ B1,
    const float* __restrict__ W2, const float* __restrict__ B2,
    const float* __restrict__ W3, const float* __restrict__ B3,
    float* __restrict__ g)
{
    __shared__ float R[LDSF];   // 9.6 KB

    const int t    = threadIdx.x;
    const int str  = blockIdx.x >> 2;
    const int slot = blockIdx.x & 3;
    const float inv = 1.0f / (float)(TBL - 1);

    float x_lo = (float)(str * 64) * inv;
    int klo_b = (int)ceilf(16.0f * x_lo - 2.36f);
    const int k  = klo_b + slot;          // block-uniform
    const int kc = min(max(k, 0), KSUB - 1);

    // ---- stage weights: W1/W2 transposed (stride 36), tail linear ----
    {
        float4 v1 = reinterpret_cast<const float4*>(&W1[kc * NW * NW])[t];
        float4 v2 = reinterpret_cast<const float4*>(&W2[kc * NW * NW])[t];
        int r = (4 * t) >> 5;        // source row (output index)
        int c = (4 * t) & 31;        // source col (input index)
        R[OW1T + (c + 0) * STR36 + r] = v1.x;
        R[OW1T + (c + 1) * STR36 + r] = v1.y;
        R[OW1T + (c + 2) * STR36 + r] = v1.z;
        R[OW1T + (c + 3) * STR36 + r] = v1.w;
        R[OW2T + (c + 0) * STR36 + r] = v2.x;
        R[OW2T + (c + 1) * STR36 + r] = v2.y;
        R[OW2T + (c + 2) * STR36 + r] = v2.z;
        R[OW2T + (c + 3) * STR36 + r] = v2.w;
        if (t < 160) {
            const int a = t >> 5, e = t & 31;
            const float* sp = (a == 0) ? &W0[kc * NW] :
                              (a == 1) ? &B0[kc * NW] :
                              (a == 2) ? &B1[kc * NW] :
                              (a == 3) ? &B2[kc * NW] : &W3[kc * NW];
            R[OT0 + t] = sp[e];
        }
    }
    __syncthreads();

    // ---- lane roles ----
    const int m  = t & 3;                 // row-group
    const int m8 = m << 3;
    const int p  = (t >> 2) & 15;         // point within wave
    const int wv = t >> 6;                // wave id
    const int pi = str * 64 + wv * 16 + p;
    const float xg = (float)pi * inv;

    const float INVS = 10.958904109589041f;  // 1/0.09125 (uniform scale)
    const float ctr  = ((float)kc + 0.5f) * 0.0625f;
    const float xn = (xg - ctr) * INVS;

    // layer 0: lane's 8 rows
    float h[8], h2[8];
#pragma unroll
    for (int j = 0; j < 8; ++j) {
        float w0 = R[OT0 + m8 + j];
        float b0 = R[OT0 + 32 + m8 + j];
        h[j] = fast_tanh(fmaf(w0, xn, b0));
    }
    // layers 1 & 2 (quad-split)
    QLAYER(OW1T, OT0 + 64, h, h2);
    QLAYER(OW2T, OT0 + 96, h2, h);
    // layer 3: partial dot + quad reduce
    float part = 0.0f;
#pragma unroll
    for (int j = 0; j < 8; ++j)
        part = fmaf(R[OT0 + 128 + m8 + j], h[j], part);
    part += __shfl_xor(part, 1);
    part += __shfl_xor(part, 2);

    const bool act = (k >= 0) && (k < KSUB);
    float wgt = window_w(xg, kc);
    float val = act ? wgt * (part + B3[kc]) : 0.0f;
    if (m == 0) g[pi * 4 + slot] = val;
}

static __device__ __forceinline__ float eval_point(
    float xj, const float* __restrict__ g)
{
    const float scaleT = (float)(TBL - 1);
    float t = fminf(fmaxf(xj * scaleT, 0.0f), scaleT);
    int i0 = (int)t;
    if (i0 > TBL - 2) i0 = TBL - 2;
    float f = t - (float)i0;
    float4 a = *reinterpret_cast<const float4*>(&g[i0 * 4]);
    float4 b = *reinterpret_cast<const float4*>(&g[i0 * 4 + 4]);
    float n0 = (a.x + a.y) + (a.z + a.w);
    float n1 = (b.x + b.y) + (b.z + b.w);
    float num = fmaf(f, n1 - n0, n0);
    float den = den_analytic(xj);
    return num * __builtin_amdgcn_rcpf(den + 1e-12f);
}

__global__ void eval_lerp(const float* __restrict__ x,
                          const float* __restrict__ g,
                          float* __restrict__ out, int N)
{
    int idx = blockIdx.x * blockDim.x + threadIdx.x;
    int base = idx * 4;
    if (base + 3 < N) {
        float4 xv = *reinterpret_cast<const float4*>(&x[base]);
        float4 r;
        r.x = eval_point(xv.x, g);
        r.y = eval_point(xv.y, g);
        r.z = eval_point(xv.z, g);
        r.w = eval_point(xv.w, g);
        *reinterpret_cast<float4*>(&out[base]) = r;
    } else {
        for (int j = base; j < N; ++j) out[j] = eval_point(x[j], g);
    }
}

// ---- fallback path (tiny ws only): direct evaluation via global loads ----
static __device__ __forceinline__ float subnet_eval_g(
    float xn, int kc,
    const float* __restrict__ W0, const float* __restrict__ B0,
    const float* __restrict__ W1, const float* __restrict__ B1,
    const float* __restrict__ W2, const float* __restrict__ B2,
    const float* __restrict__ W3, const float* __restrict__ B3)
{
    float h0[NW], h1[NW];
#pragma unroll
    for (int o = 0; o < NW; ++o)
        h0[o] = fast_tanh(fmaf(W0[kc * NW + o], xn, B0[kc * NW + o]));
#pragma unroll
    for (int o = 0; o < NW; ++o) {
        float a = B1[kc * NW + o];
        const float* row = &W1[kc * NW * NW + o * NW];
#pragma unroll
        for (int j = 0; j < NW; ++j) a = fmaf(row[j], h0[j], a);
        h1[o] = fast_tanh(a);
    }
#pragma unroll
    for (int o = 0; o < NW; ++o) {
        float a = B2[kc * NW + o];
        const float* row = &W2[kc * NW * NW + o * NW];
#pragma unroll
        for (int j = 0; j < NW; ++j) a = fmaf(row[j], h1[j], a);
        h0[o] = fast_tanh(a);
    }
    float a = B3[kc];
#pragma unroll
    for (int j = 0; j < NW; ++j) a = fmaf(W3[kc * NW + j], h0[j], a);
    return a;
}

__global__ void direct_eval(
    const float* __restrict__ x,
    const float* __restrict__ W0, const float* __restrict__ B0,
    const float* __restrict__ W1, const float* __restrict__ B1,
    const float* __restrict__ W2, const float* __restrict__ B2,
    const float* __restrict__ W3, const float* __restrict__ B3,
    float* __restrict__ out, int N)
{
    int n = blockIdx.x * blockDim.x + threadIdx.x;
    if (n >= N) return;
    float xv = x[n];
    float num = 0.f, den = 0.f;
    for (int k = 0; k < KSUB; ++k) {
        float w = window_w(xv, k);
        if (w <= 0.0f) continue;
        float xn = (xv - ((float)k + 0.5f) * 0.0625f) * 10.958904109589041f;
        float o = subnet_eval_g(xn, k, W0, B0, W1, B1, W2, B2, W3, B3);
        num += w * o;
        den += w;
    }
    out[n] = num * __builtin_amdgcn_rcpf(den + 1e-12f);
}

extern "C" void kernel_launch(void* const* d_in, const int* in_sizes, int n_in,
                              void* d_out, int out_size, void* d_ws, size_t ws_size,
                              hipStream_t stream) {
    const float* x  = (const float*)d_in[0];
    const float* W0 = (const float*)d_in[1];
    const float* B0 = (const float*)d_in[2];
    const float* W1 = (const float*)d_in[3];
    const float* B1 = (const float*)d_in[4];
    const float* W2 = (const float*)d_in[5];
    const float* B2 = (const float*)d_in[6];
    const float* W3 = (const float*)d_in[7];
    const float* B3 = (const float*)d_in[8];
    float* out = (float*)d_out;
    const int N = in_sizes[0];

    if ((size_t)TBL * 4 * sizeof(float) <= ws_size) {
        float* g = (float*)d_ws;
        build_tables<<<NSTR * SLOTS, 256, 0, stream>>>(
            W0, B0, W1, B1, W2, B2, W3, B3, g);
        int nv = (N + 3) / 4;
        eval_lerp<<<(nv + 255) / 256, 256, 0, stream>>>(x, g, out, N);
    } else {
        direct_eval<<<(N + 255) / 256, 256, 0, stream>>>(
            x, W0, B0, W1, B1, W2, B2, W3, B3, out, N);
    }
}

// Round 16
// 14.328 us; speedup vs baseline: 12.8831x; 1.2900x over previous
//
#include <hip/hip_runtime.h>
#include <math.h>

// FBPINN: out(x) = sum_k w_k(x)*subnet_k(x) / sum_k w_k(x), x scalar in [0,1].
// Two dispatches:
//  1) build_tables, POINT-PER-QUAD: block = (64-pt stretch, slot); 256 thr.
//     Lane = (point p, row-group m): lane computes 8 of 32 rows per layer.
//     Cross-lane activation exchange via DPP quad_perm (v_mov_dpp, VALU,
//     ~2cyc) instead of __shfl_xor/ds_swizzle -- R15 analysis: the 64
//     shuffles/lane were DS-pipe ops sharing the same CU LDS pipe as the
//     weight reads, making build LDS-throughput bound (~9us). T halved to
//     8192 (throughput-bound => work scales; R9's null result was the old
//     latency regime). Weights in LDS transposed, stride 36 (b128-aligned,
//     m-groups hit banks {0,8,16,24}, conflict-free broadcast).
//  2) eval_lerp: two float4 loads fetch 8 interleaved table entries; sum of
//     4 lerps = lerp of sum; denominator ANALYTIC. (R9/R13/R14-validated.)
// Lerp error ~1e-5 at TBL=8192 << 7.3e-3 threshold (bf16 floor 1.95e-3).

#define KSUB 16
#define NW 32
#define TBL 8192
#define NSTR (TBL / 64)       // 128 stretches
#define SLOTS 4               // active-k union over 64-pt stretch <= 4 ints
#define STR36 36              // padded transposed row stride (floats)
// LDS offsets (floats)
#define OW1T 0                // [32][36] transposed W1
#define OW2T 1152             // [32][36] transposed W2
#define OT0  2304             // W0[32] B0[32] B1[32] B2[32] W3[32]
#define LDSF 2464

// tanh(x) = 1 - 2/(exp(2x)+1); v_exp_f32 is exp2 -> scale by 2*log2(e).
static __device__ __forceinline__ float fast_tanh(float v) {
    float e = __builtin_amdgcn_exp2f(v * 2.8853900817779268f);
    return 1.0f - 2.0f * __builtin_amdgcn_rcpf(e + 1.0f);
}

static __device__ __forceinline__ float cos_pi(float u) {
    return __builtin_amdgcn_cosf(0.5f * u);   // v_cos takes revolutions
}

static __device__ __forceinline__ float window_w(float x, int k) {
    const float invTW = 20.0f;  // 1/0.05
    float xmin = (float)k * 0.0625f - 0.06f;
    float xmax = (float)(k + 1) * 0.0625f + 0.06f;
    float up = (x - xmin + 0.025f) * invTW;
    float dn = (xmax + 0.025f - x) * invTW;
    up = fminf(fmaxf(up, 0.0f), 1.0f);
    dn = fminf(fmaxf(dn, 0.0f), 1.0f);
    return 0.25f * (1.0f - cos_pi(up)) * (1.0f - cos_pi(dn));
}

// Active subnets at x: k in (16x-2.36, 16x+1.36) => at most 4, klo..klo+3.
static __device__ __forceinline__ float den_analytic(float xv) {
    int klo = (int)ceilf(16.0f * xv - 2.36f);
    float den = 0.f;
#pragma unroll
    for (int j = 0; j < 4; ++j) {
        int k = klo + j;
        if (k >= 0 && k < KSUB) den += window_w(xv, k);
    }
    return den;
}

// DPP quad_perm lane exchange within each aligned quad (VALU, no DS pipe).
// ctrl = p0|p1<<2|p2<<4|p3<<6 : xor1=0xB1, xor2=0x4E, xor3=0x1B.
template <int CTRL>
static __device__ __forceinline__ float dpp_quad(float v) {
    return __uint_as_float(__builtin_amdgcn_mov_dpp(
        __float_as_uint(v), CTRL, 0xF, 0xF, true));
}
static __device__ __forceinline__ float quad_xor(float v, int e) {
    // e is a compile-time constant under full unroll
    if (e == 1) return dpp_quad<0xB1>(v);
    if (e == 2) return dpp_quad<0x4E>(v);
    if (e == 3) return dpp_quad<0x1B>(v);
    return v;
}

// One hidden layer, quad-split: lane owns rows [m*8, m*8+8).
#define QLAYER(WTOFS, BOFS, hin, hout)                                      \
    {                                                                       \
        float acc[8];                                                       \
        {                                                                   \
            float4 bA = *reinterpret_cast<const float4*>(&R[(BOFS) + m8]);  \
            float4 bB = *reinterpret_cast<const float4*>(&R[(BOFS) + m8 + 4]); \
            acc[0] = bA.x; acc[1] = bA.y; acc[2] = bA.z; acc[3] = bA.w;     \
            acc[4] = bB.x; acc[5] = bB.y; acc[6] = bB.z; acc[7] = bB.w;     \
        }                                                                   \
        _Pragma("unroll")                                                   \
        for (int e = 0; e < 4; ++e) {                                       \
            const int src8 = ((m ^ e) << 3);                                \
            _Pragma("unroll")                                               \
            for (int j2 = 0; j2 < 8; ++j2) {                                \
                float v = quad_xor(hin[j2], e);                             \
                float4 wA = *reinterpret_cast<const float4*>(               \
                    &R[(WTOFS) + (src8 + j2) * STR36 + m8]);                \
                float4 wB = *reinterpret_cast<const float4*>(               \
                    &R[(WTOFS) + (src8 + j2) * STR36 + m8 + 4]);            \
                acc[0] = fmaf(wA.x, v, acc[0]);                             \
                acc[1] = fmaf(wA.y, v, acc[1]);                             \
                acc[2] = fmaf(wA.z, v, acc[2]);                             \
                acc[3] = fmaf(wA.w, v, acc[3]);                             \
                acc[4] = fmaf(wB.x, v, acc[4]);                             \
                acc[5] = fmaf(wB.y, v, acc[5]);                             \
                acc[6] = fmaf(wB.z, v, acc[6]);                             \
                acc[7] = fmaf(wB.w, v, acc[7]);                             \
            }                                                               \
        }                                                                   \
        _Pragma("unroll")                                                   \
        for (int j = 0; j < 8; ++j) hout[j] = fast_tanh(acc[j]);            \
    }

// grid = NSTR*SLOTS = 512 blocks x 256 threads (4 waves, 16 pts/wave).
__global__ __launch_bounds__(256) void build_tables(
    const float* __restrict__ W0, const float* __restrict__ B0,
    const float* __restrict__ W1, const float* __restrict__ B1,
    const float* __restrict__ W2, const float* __restrict__ B2,
    const float* __restrict__ W3, const float* __restrict__ B3,
    float* __restrict__ g)
{
    __shared__ float R[LDSF];   // 9.6 KB

    const int t    = threadIdx.x;
    const int str  = blockIdx.x >> 2;
    const int slot = blockIdx.x & 3;
    const float inv = 1.0f / (float)(TBL - 1);

    float x_lo = (float)(str * 64) * inv;
    int klo_b = (int)ceilf(16.0f * x_lo - 2.36f);
    const int k  = klo_b + slot;          // block-uniform
    const int kc = min(max(k, 0), KSUB - 1);

    // ---- stage weights: W1/W2 transposed (stride 36), tail linear ----
    {
        float4 v1 = reinterpret_cast<const float4*>(&W1[kc * NW * NW])[t];
        float4 v2 = reinterpret_cast<const float4*>(&W2[kc * NW * NW])[t];
        int r = (4 * t) >> 5;        // source row (output index)
        int c = (4 * t) & 31;        // source col (input index)
        R[OW1T + (c + 0) * STR36 + r] = v1.x;
        R[OW1T + (c + 1) * STR36 + r] = v1.y;
        R[OW1T + (c + 2) * STR36 + r] = v1.z;
        R[OW1T + (c + 3) * STR36 + r] = v1.w;
        R[OW2T + (c + 0) * STR36 + r] = v2.x;
        R[OW2T + (c + 1) * STR36 + r] = v2.y;
        R[OW2T + (c + 2) * STR36 + r] = v2.z;
        R[OW2T + (c + 3) * STR36 + r] = v2.w;
        if (t < 160) {
            const int a = t >> 5, e = t & 31;
            const float* sp = (a == 0) ? &W0[kc * NW] :
                              (a == 1) ? &B0[kc * NW] :
                              (a == 2) ? &B1[kc * NW] :
                              (a == 3) ? &B2[kc * NW] : &W3[kc * NW];
            R[OT0 + t] = sp[e];
        }
    }
    __syncthreads();

    // ---- lane roles ----
    const int m  = t & 3;                 // row-group
    const int m8 = m << 3;
    const int p  = (t >> 2) & 15;         // point within wave
    const int wv = t >> 6;                // wave id
    const int pi = str * 64 + wv * 16 + p;
    const float xg = (float)pi * inv;

    const float INVS = 10.958904109589041f;  // 1/0.09125 (uniform scale)
    const float ctr  = ((float)kc + 0.5f) * 0.0625f;
    const float xn = (xg - ctr) * INVS;

    // layer 0: lane's 8 rows
    float h[8], h2[8];
#pragma unroll
    for (int j = 0; j < 8; ++j) {
        float w0 = R[OT0 + m8 + j];
        float b0 = R[OT0 + 32 + m8 + j];
        h[j] = fast_tanh(fmaf(w0, xn, b0));
    }
    // layers 1 & 2 (quad-split, DPP exchange)
    QLAYER(OW1T, OT0 + 64, h, h2);
    QLAYER(OW2T, OT0 + 96, h2, h);
    // layer 3: partial dot + quad reduce (DPP)
    float part = 0.0f;
#pragma unroll
    for (int j = 0; j < 8; ++j)
        part = fmaf(R[OT0 + 128 + m8 + j], h[j], part);
    part += dpp_quad<0xB1>(part);
    part += dpp_quad<0x4E>(part);

    const bool act = (k >= 0) && (k < KSUB);
    float wgt = window_w(xg, kc);
    float val = act ? wgt * (part + B3[kc]) : 0.0f;
    if (m == 0) g[pi * 4 + slot] = val;
}

static __device__ __forceinline__ float eval_point(
    float xj, const float* __restrict__ g)
{
    const float scaleT = (float)(TBL - 1);
    float t = fminf(fmaxf(xj * scaleT, 0.0f), scaleT);
    int i0 = (int)t;
    if (i0 > TBL - 2) i0 = TBL - 2;
    float f = t - (float)i0;
    float4 a = *reinterpret_cast<const float4*>(&g[i0 * 4]);
    float4 b = *reinterpret_cast<const float4*>(&g[i0 * 4 + 4]);
    float n0 = (a.x + a.y) + (a.z + a.w);
    float n1 = (b.x + b.y) + (b.z + b.w);
    float num = fmaf(f, n1 - n0, n0);
    float den = den_analytic(xj);
    return num * __builtin_amdgcn_rcpf(den + 1e-12f);
}

__global__ void eval_lerp(const float* __restrict__ x,
                          const float* __restrict__ g,
                          float* __restrict__ out, int N)
{
    int idx = blockIdx.x * blockDim.x + threadIdx.x;
    int base = idx * 4;
    if (base + 3 < N) {
        float4 xv = *reinterpret_cast<const float4*>(&x[base]);
        float4 r;
        r.x = eval_point(xv.x, g);
        r.y = eval_point(xv.y, g);
        r.z = eval_point(xv.z, g);
        r.w = eval_point(xv.w, g);
        *reinterpret_cast<float4*>(&out[base]) = r;
    } else {
        for (int j = base; j < N; ++j) out[j] = eval_point(x[j], g);
    }
}

// ---- fallback path (tiny ws only): direct evaluation via global loads ----
static __device__ __forceinline__ float subnet_eval_g(
    float xn, int kc,
    const float* __restrict__ W0, const float* __restrict__ B0,
    const float* __restrict__ W1, const float* __restrict__ B1,
    const float* __restrict__ W2, const float* __restrict__ B2,
    const float* __restrict__ W3, const float* __restrict__ B3)
{
    float h0[NW], h1[NW];
#pragma unroll
    for (int o = 0; o < NW; ++o)
        h0[o] = fast_tanh(fmaf(W0[kc * NW + o], xn, B0[kc * NW + o]));
#pragma unroll
    for (int o = 0; o < NW; ++o) {
        float a = B1[kc * NW + o];
        const float* row = &W1[kc * NW * NW + o * NW];
#pragma unroll
        for (int j = 0; j < NW; ++j) a = fmaf(row[j], h0[j], a);
        h1[o] = fast_tanh(a);
    }
#pragma unroll
    for (int o = 0; o < NW; ++o) {
        float a = B2[kc * NW + o];
        const float* row = &W2[kc * NW * NW + o * NW];
#pragma unroll
        for (int j = 0; j < NW; ++j) a = fmaf(row[j], h1[j], a);
        h0[o] = fast_tanh(a);
    }
    float a = B3[kc];
#pragma unroll
    for (int j = 0; j < NW; ++j) a = fmaf(W3[kc * NW + j], h0[j], a);
    return a;
}

__global__ void direct_eval(
    const float* __restrict__ x,
    const float* __restrict__ W0, const float* __restrict__ B0,
    const float* __restrict__ W1, const float* __restrict__ B1,
    const float* __restrict__ W2, const float* __restrict__ B2,
    const float* __restrict__ W3, const float* __restrict__ B3,
    float* __restrict__ out, int N)
{
    int n = blockIdx.x * blockDim.x + threadIdx.x;
    if (n >= N) return;
    float xv = x[n];
    float num = 0.f, den = 0.f;
    for (int k = 0; k < KSUB; ++k) {
        float w = window_w(xv, k);
        if (w <= 0.0f) continue;
        float xn = (xv - ((float)k + 0.5f) * 0.0625f) * 10.958904109589041f;
        float o = subnet_eval_g(xn, k, W0, B0, W1, B1, W2, B2, W3, B3);
        num += w * o;
        den += w;
    }
    out[n] = num * __builtin_amdgcn_rcpf(den + 1e-12f);
}

extern "C" void kernel_launch(void* const* d_in, const int* in_sizes, int n_in,
                              void* d_out, int out_size, void* d_ws, size_t ws_size,
                              hipStream_t stream) {
    const float* x  = (const float*)d_in[0];
    const float* W0 = (const float*)d_in[1];
    const float* B0 = (const float*)d_in[2];
    const float* W1 = (const float*)d_in[3];
    const float* B1 = (const float*)d_in[4];
    const float* W2 = (const float*)d_in[5];
    const float* B2 = (const float*)d_in[6];
    const float* W3 = (const float*)d_in[7];
    const float* B3 = (const float*)d_in[8];
    float* out = (float*)d_out;
    const int N = in_sizes[0];

    if ((size_t)TBL * 4 * sizeof(float) <= ws_size) {
        float* g = (float*)d_ws;
        build_tables<<<NSTR * SLOTS, 256, 0, stream>>>(
            W0, B0, W1, B1, W2, B2, W3, B3, g);
        int nv = (N + 3) / 4;
        eval_lerp<<<(nv + 255) / 256, 256, 0, stream>>>(x, g, out, N);
    } else {
        direct_eval<<<(N + 255) / 256, 256, 0, stream>>>(
            x, W0, B0, W1, B1, W2, B2, W3, B3, out, N);
    }
}

// Round 17
// 13.340 us; speedup vs baseline: 13.8378x; 1.0741x over previous
//
#include <hip/hip_runtime.h>
#include <math.h>

// FBPINN: out(x) = sum_k w_k(x)*subnet_k(x) / sum_k w_k(x), x scalar in [0,1].
// Two dispatches:
//  1) build_tables, POINT-PER-QUAD: block = (64-pt stretch, slot); 256 thr.
//     Lane = (point p, row-group m): lane computes 8 of 32 rows per layer.
//     Cross-lane activation exchange via DPP quad_perm (VALU, ~2cyc, zero
//     DS-pipe use). Weights in LDS transposed, stride 36 (b128-aligned,
//     m-groups hit banks {0,8,16,24}, conflict-free broadcast).
//     Build is DS-pipe-throughput bound (confirmed R15/R16: DPP removal and
//     T-halving both moved time as the model predicts) -> T=4096 halves the
//     weight-read stream again: ~134 b128/lane x 4 waves x 1 block/CU x
//     12cyc ~ 6.4K cyc ~ 2.7us.
//  2) eval_lerp: two float4 loads fetch 8 interleaved table entries; sum of
//     4 lerps = lerp of sum; denominator ANALYTIC (<=4 cosine windows).
// Lerp error ~4e-5 at TBL=4096 << 7.3e-3 threshold (bf16 floor 1.95e-3).
// Slot coverage at T=4096: 3.72 + 16*(63/4095) = 3.966 < 4 -> 4 slots cover.

#define KSUB 16
#define NW 32
#define TBL 4096
#define NSTR (TBL / 64)       // 64 stretches
#define SLOTS 4               // active-k union over 64-pt stretch <= 4 ints
#define STR36 36              // padded transposed row stride (floats)
// LDS offsets (floats)
#define OW1T 0                // [32][36] transposed W1
#define OW2T 1152             // [32][36] transposed W2
#define OT0  2304             // W0[32] B0[32] B1[32] B2[32] W3[32]
#define LDSF 2464

// tanh(x) = 1 - 2/(exp(2x)+1); v_exp_f32 is exp2 -> scale by 2*log2(e).
static __device__ __forceinline__ float fast_tanh(float v) {
    float e = __builtin_amdgcn_exp2f(v * 2.8853900817779268f);
    return 1.0f - 2.0f * __builtin_amdgcn_rcpf(e + 1.0f);
}

static __device__ __forceinline__ float cos_pi(float u) {
    return __builtin_amdgcn_cosf(0.5f * u);   // v_cos takes revolutions
}

static __device__ __forceinline__ float window_w(float x, int k) {
    const float invTW = 20.0f;  // 1/0.05
    float xmin = (float)k * 0.0625f - 0.06f;
    float xmax = (float)(k + 1) * 0.0625f + 0.06f;
    float up = (x - xmin + 0.025f) * invTW;
    float dn = (xmax + 0.025f - x) * invTW;
    up = fminf(fmaxf(up, 0.0f), 1.0f);
    dn = fminf(fmaxf(dn, 0.0f), 1.0f);
    return 0.25f * (1.0f - cos_pi(up)) * (1.0f - cos_pi(dn));
}

// Active subnets at x: k in (16x-2.36, 16x+1.36) => at most 4, klo..klo+3.
static __device__ __forceinline__ float den_analytic(float xv) {
    int klo = (int)ceilf(16.0f * xv - 2.36f);
    float den = 0.f;
#pragma unroll
    for (int j = 0; j < 4; ++j) {
        int k = klo + j;
        if (k >= 0 && k < KSUB) den += window_w(xv, k);
    }
    return den;
}

// DPP quad_perm lane exchange within each aligned quad (VALU, no DS pipe).
// ctrl = p0|p1<<2|p2<<4|p3<<6 : xor1=0xB1, xor2=0x4E, xor3=0x1B.
template <int CTRL>
static __device__ __forceinline__ float dpp_quad(float v) {
    return __uint_as_float(__builtin_amdgcn_mov_dpp(
        __float_as_uint(v), CTRL, 0xF, 0xF, true));
}
static __device__ __forceinline__ float quad_xor(float v, int e) {
    // e is a compile-time constant under full unroll
    if (e == 1) return dpp_quad<0xB1>(v);
    if (e == 2) return dpp_quad<0x4E>(v);
    if (e == 3) return dpp_quad<0x1B>(v);
    return v;
}

// One hidden layer, quad-split: lane owns rows [m*8, m*8+8).
#define QLAYER(WTOFS, BOFS, hin, hout)                                      \
    {                                                                       \
        float acc[8];                                                       \
        {                                                                   \
            float4 bA = *reinterpret_cast<const float4*>(&R[(BOFS) + m8]);  \
            float4 bB = *reinterpret_cast<const float4*>(&R[(BOFS) + m8 + 4]); \
            acc[0] = bA.x; acc[1] = bA.y; acc[2] = bA.z; acc[3] = bA.w;     \
            acc[4] = bB.x; acc[5] = bB.y; acc[6] = bB.z; acc[7] = bB.w;     \
        }                                                                   \
        _Pragma("unroll")                                                   \
        for (int e = 0; e < 4; ++e) {                                       \
            const int src8 = ((m ^ e) << 3);                                \
            _Pragma("unroll")                                               \
            for (int j2 = 0; j2 < 8; ++j2) {                                \
                float v = quad_xor(hin[j2], e);                             \
                float4 wA = *reinterpret_cast<const float4*>(               \
                    &R[(WTOFS) + (src8 + j2) * STR36 + m8]);                \
                float4 wB = *reinterpret_cast<const float4*>(               \
                    &R[(WTOFS) + (src8 + j2) * STR36 + m8 + 4]);            \
                acc[0] = fmaf(wA.x, v, acc[0]);                             \
                acc[1] = fmaf(wA.y, v, acc[1]);                             \
                acc[2] = fmaf(wA.z, v, acc[2]);                             \
                acc[3] = fmaf(wA.w, v, acc[3]);                             \
                acc[4] = fmaf(wB.x, v, acc[4]);                             \
                acc[5] = fmaf(wB.y, v, acc[5]);                             \
                acc[6] = fmaf(wB.z, v, acc[6]);                             \
                acc[7] = fmaf(wB.w, v, acc[7]);                             \
            }                                                               \
        }                                                                   \
        _Pragma("unroll")                                                   \
        for (int j = 0; j < 8; ++j) hout[j] = fast_tanh(acc[j]);            \
    }

// grid = NSTR*SLOTS = 256 blocks x 256 threads (4 waves, 16 pts/wave).
__global__ __launch_bounds__(256) void build_tables(
    const float* __restrict__ W0, const float* __restrict__ B0,
    const float* __restrict__ W1, const float* __restrict__ B1,
    const float* __restrict__ W2, const float* __restrict__ B2,
    const float* __restrict__ W3, const float* __restrict__ B3,
    float* __restrict__ g)
{
    __shared__ float R[LDSF];   // 9.6 KB

    const int t    = threadIdx.x;
    const int str  = blockIdx.x >> 2;
    const int slot = blockIdx.x & 3;
    const float inv = 1.0f / (float)(TBL - 1);

    float x_lo = (float)(str * 64) * inv;
    int klo_b = (int)ceilf(16.0f * x_lo - 2.36f);
    const int k  = klo_b + slot;          // block-uniform
    const int kc = min(max(k, 0), KSUB - 1);

    // ---- stage weights: W1/W2 transposed (stride 36), tail linear ----
    {
        float4 v1 = reinterpret_cast<const float4*>(&W1[kc * NW * NW])[t];
        float4 v2 = reinterpret_cast<const float4*>(&W2[kc * NW * NW])[t];
        int r = (4 * t) >> 5;        // source row (output index)
        int c = (4 * t) & 31;        // source col (input index)
        R[OW1T + (c + 0) * STR36 + r] = v1.x;
        R[OW1T + (c + 1) * STR36 + r] = v1.y;
        R[OW1T + (c + 2) * STR36 + r] = v1.z;
        R[OW1T + (c + 3) * STR36 + r] = v1.w;
        R[OW2T + (c + 0) * STR36 + r] = v2.x;
        R[OW2T + (c + 1) * STR36 + r] = v2.y;
        R[OW2T + (c + 2) * STR36 + r] = v2.z;
        R[OW2T + (c + 3) * STR36 + r] = v2.w;
        if (t < 160) {
            const int a = t >> 5, e = t & 31;
            const float* sp = (a == 0) ? &W0[kc * NW] :
                              (a == 1) ? &B0[kc * NW] :
                              (a == 2) ? &B1[kc * NW] :
                              (a == 3) ? &B2[kc * NW] : &W3[kc * NW];
            R[OT0 + t] = sp[e];
        }
    }
    __syncthreads();

    // ---- lane roles ----
    const int m  = t & 3;                 // row-group
    const int m8 = m << 3;
    const int p  = (t >> 2) & 15;         // point within wave
    const int wv = t >> 6;                // wave id
    const int pi = str * 64 + wv * 16 + p;
    const float xg = (float)pi * inv;

    const float INVS = 10.958904109589041f;  // 1/0.09125 (uniform scale)
    const float ctr  = ((float)kc + 0.5f) * 0.0625f;
    const float xn = (xg - ctr) * INVS;

    // layer 0: lane's 8 rows
    float h[8], h2[8];
#pragma unroll
    for (int j = 0; j < 8; ++j) {
        float w0 = R[OT0 + m8 + j];
        float b0 = R[OT0 + 32 + m8 + j];
        h[j] = fast_tanh(fmaf(w0, xn, b0));
    }
    // layers 1 & 2 (quad-split, DPP exchange)
    QLAYER(OW1T, OT0 + 64, h, h2);
    QLAYER(OW2T, OT0 + 96, h2, h);
    // layer 3: partial dot + quad reduce (DPP)
    float part = 0.0f;
#pragma unroll
    for (int j = 0; j < 8; ++j)
        part = fmaf(R[OT0 + 128 + m8 + j], h[j], part);
    part += dpp_quad<0xB1>(part);
    part += dpp_quad<0x4E>(part);

    const bool act = (k >= 0) && (k < KSUB);
    float wgt = window_w(xg, kc);
    float val = act ? wgt * (part + B3[kc]) : 0.0f;
    if (m == 0) g[pi * 4 + slot] = val;
}

static __device__ __forceinline__ float eval_point(
    float xj, const float* __restrict__ g)
{
    const float scaleT = (float)(TBL - 1);
    float t = fminf(fmaxf(xj * scaleT, 0.0f), scaleT);
    int i0 = (int)t;
    if (i0 > TBL - 2) i0 = TBL - 2;
    float f = t - (float)i0;
    float4 a = *reinterpret_cast<const float4*>(&g[i0 * 4]);
    float4 b = *reinterpret_cast<const float4*>(&g[i0 * 4 + 4]);
    float n0 = (a.x + a.y) + (a.z + a.w);
    float n1 = (b.x + b.y) + (b.z + b.w);
    float num = fmaf(f, n1 - n0, n0);
    float den = den_analytic(xj);
    return num * __builtin_amdgcn_rcpf(den + 1e-12f);
}

__global__ void eval_lerp(const float* __restrict__ x,
                          const float* __restrict__ g,
                          float* __restrict__ out, int N)
{
    int idx = blockIdx.x * blockDim.x + threadIdx.x;
    int base = idx * 4;
    if (base + 3 < N) {
        float4 xv = *reinterpret_cast<const float4*>(&x[base]);
        float4 r;
        r.x = eval_point(xv.x, g);
        r.y = eval_point(xv.y, g);
        r.z = eval_point(xv.z, g);
        r.w = eval_point(xv.w, g);
        *reinterpret_cast<float4*>(&out[base]) = r;
    } else {
        for (int j = base; j < N; ++j) out[j] = eval_point(x[j], g);
    }
}

// ---- fallback path (tiny ws only): direct evaluation via global loads ----
static __device__ __forceinline__ float subnet_eval_g(
    float xn, int kc,
    const float* __restrict__ W0, const float* __restrict__ B0,
    const float* __restrict__ W1, const float* __restrict__ B1,
    const float* __restrict__ W2, const float* __restrict__ B2,
    const float* __restrict__ W3, const float* __restrict__ B3)
{
    float h0[NW], h1[NW];
#pragma unroll
    for (int o = 0; o < NW; ++o)
        h0[o] = fast_tanh(fmaf(W0[kc * NW + o], xn, B0[kc * NW + o]));
#pragma unroll
    for (int o = 0; o < NW; ++o) {
        float a = B1[kc * NW + o];
        const float* row = &W1[kc * NW * NW + o * NW];
#pragma unroll
        for (int j = 0; j < NW; ++j) a = fmaf(row[j], h0[j], a);
        h1[o] = fast_tanh(a);
    }
#pragma unroll
    for (int o = 0; o < NW; ++o) {
        float a = B2[kc * NW + o];
        const float* row = &W2[kc * NW * NW + o * NW];
#pragma unroll
        for (int j = 0; j < NW; ++j) a = fmaf(row[j], h1[j], a);
        h0[o] = fast_tanh(a);
    }
    float a = B3[kc];
#pragma unroll
    for (int j = 0; j < NW; ++j) a = fmaf(W3[kc * NW + j], h0[j], a);
    return a;
}

__global__ void direct_eval(
    const float* __restrict__ x,
    const float* __restrict__ W0, const float* __restrict__ B0,
    const float* __restrict__ W1, const float* __restrict__ B1,
    const float* __restrict__ W2, const float* __restrict__ B2,
    const float* __restrict__ W3, const float* __restrict__ B3,
    float* __restrict__ out, int N)
{
    int n = blockIdx.x * blockDim.x + threadIdx.x;
    if (n >= N) return;
    float xv = x[n];
    float num = 0.f, den = 0.f;
    for (int k = 0; k < KSUB; ++k) {
        float w = window_w(xv, k);
        if (w <= 0.0f) continue;
        float xn = (xv - ((float)k + 0.5f) * 0.0625f) * 10.958904109589041f;
        float o = subnet_eval_g(xn, k, W0, B0, W1, B1, W2, B2, W3, B3);
        num += w * o;
        den += w;
    }
    out[n] = num * __builtin_amdgcn_rcpf(den + 1e-12f);
}

extern "C" void kernel_launch(void* const* d_in, const int* in_sizes, int n_in,
                              void* d_out, int out_size, void* d_ws, size_t ws_size,
                              hipStream_t stream) {
    const float* x  = (const float*)d_in[0];
    const float* W0 = (const float*)d_in[1];
    const float* B0 = (const float*)d_in[2];
    const float* W1 = (const float*)d_in[3];
    const float* B1 = (const float*)d_in[4];
    const float* W2 = (const float*)d_in[5];
    const float* B2 = (const float*)d_in[6];
    const float* W3 = (const float*)d_in[7];
    const float* B3 = (const float*)d_in[8];
    float* out = (float*)d_out;
    const int N = in_sizes[0];

    if ((size_t)TBL * 4 * sizeof(float) <= ws_size) {
        float* g = (float*)d_ws;
        build_tables<<<NSTR * SLOTS, 256, 0, stream>>>(
            W0, B0, W1, B1, W2, B2, W3, B3, g);
        int nv = (N + 3) / 4;
        eval_lerp<<<(nv + 255) / 256, 256, 0, stream>>>(x, g, out, N);
    } else {
        direct_eval<<<(N + 255) / 256, 256, 0, stream>>>(
            x, W0, B0, W1, B1, W2, B2, W3, B3, out, N);
    }
}